// Round 14
// baseline (63.142 us; speedup 1.0000x reference)
//
#include <hip/hip_runtime.h>

#define TOKS 65536
#define ED 64
#define NE 1024
#define CH_STRIDE 4096      // 64*64
#define B_STRIDE 262144     // 64*64*64

typedef __bf16 bf16x8 __attribute__((ext_vector_type(8)));
typedef float f32x16 __attribute__((ext_vector_type(16)));
typedef unsigned short ushort_t;
typedef unsigned int uint_t;

// ws layout:
//   efrag    @ 0      : 32ct x 4ks x 64lane x 8 bf16 (hi of -2*emb) [128 KB]
//   enorm    @ 131072 : 1024 f32 (np-pairwise ||e||^2, exact)        [4 KB]
//   hist     @ 135168 : 1024 i32                                     [4 KB]
//   lossPart @ 143360 : 1024 f64                                     [8 KB]
//   cand     @ 151552 : 65536 x 6 uint32 filter keys                 [1.5 MB]

__device__ __forceinline__ ushort_t f2bf(float x) {
    uint_t u = __float_as_uint(x);
    uint_t r = u + 0x7FFFu + ((u >> 16) & 1u);   // RNE
    return (ushort_t)(r >> 16);
}

// ---- prep E: wave per code. enorm via shfl-replicated numpy pairwise (exact
// op order: 8 accumulators, 7 sequential stride-8 adds, 3-level tree).
__global__ __launch_bounds__(256) void vq_prep_e(const float* __restrict__ emb,
                                                 ushort_t* __restrict__ efrag,
                                                 float* __restrict__ enorm,
                                                 int* __restrict__ hist) {
    const int tid = threadIdx.x;
    const int w = tid >> 6, lane = tid & 63;
    const int j = blockIdx.x * 4 + w;

    const float e = emb[j * 64 + lane];
    const float sq = __fmul_rn(e, e);
    float acc = sq;
    acc = __fadd_rn(acc, __shfl_down(sq, 8, 64));
    acc = __fadd_rn(acc, __shfl_down(sq, 16, 64));
    acc = __fadd_rn(acc, __shfl_down(sq, 24, 64));
    acc = __fadd_rn(acc, __shfl_down(sq, 32, 64));
    acc = __fadd_rn(acc, __shfl_down(sq, 40, 64));
    acc = __fadd_rn(acc, __shfl_down(sq, 48, 64));
    acc = __fadd_rn(acc, __shfl_down(sq, 56, 64));
    float x = __fadd_rn(acc, __shfl_down(acc, 1, 64));
    float y = __fadd_rn(x, __shfl_down(x, 2, 64));
    float zn = __fadd_rn(y, __shfl_down(y, 4, 64));
    if (lane == 0) enorm[j] = zn;

    const ushort_t h = f2bf(-2.0f * e);
    const int ct = j >> 5, m = j & 31;
    const int ks = lane >> 4, kh = (lane >> 3) & 1, i = lane & 7;
    efrag[(size_t)((ct * 4 + ks) * 512) + (m + 32 * kh) * 8 + i] = h;

    if (blockIdx.x < 4) hist[blockIdx.x * 256 + tid] = 0;
}

// ---- SCAN: 1 wave per 32-token tile, ALL 1024 codes. Zero LDS, zero
// barriers. Top-3 keys per 512-code lane-set -> 6 keys/token to global.
__global__ __launch_bounds__(64) void vq_scan(
    const float* __restrict__ z,
    const ushort_t* __restrict__ efrag,
    uint_t* __restrict__ cand) {
    const int lane = threadIdx.x;
    const int t0 = blockIdx.x * 32;
    const int b = t0 >> 12, hw0 = t0 & 4095;
    const float* zbase = z + (size_t)b * B_STRIDE + hw0;
    const int n = lane & 31, kh = lane >> 5;

    // B-frag: bf16(z) hi-plane from global (coalesced b32 column loads)
    bf16x8 zb[4];
    #pragma unroll
    for (int ks = 0; ks < 4; ++ks) {
        #pragma unroll
        for (int i = 0; i < 8; ++i) {
            union { ushort_t u; __bf16 bh; } ca;
            ca.u = f2bf(zbase[(size_t)(ks * 16 + kh * 8 + i) * CH_STRIDE + n]);
            zb[ks][i] = ca.bh;
        }
    }

    uint_t k0 = 0xFFFFFFFFu, k1 = 0xFFFFFFFFu, k2 = 0xFFFFFFFFu;
    const bf16x8* eg = (const bf16x8*)efrag;

    bf16x8 ah0 = eg[(size_t)0 * 64 + lane];
    bf16x8 ah1 = eg[(size_t)1 * 64 + lane];
    bf16x8 ah2 = eg[(size_t)2 * 64 + lane];
    bf16x8 ah3 = eg[(size_t)3 * 64 + lane];

    for (int ct = 0; ct < 32; ++ct) {
        bf16x8 nx0, nx1, nx2, nx3;
        if (ct < 31) {                             // 1-deep prefetch
            nx0 = eg[(size_t)((ct + 1) * 4 + 0) * 64 + lane];
            nx1 = eg[(size_t)((ct + 1) * 4 + 1) * 64 + lane];
            nx2 = eg[(size_t)((ct + 1) * 4 + 2) * 64 + lane];
            nx3 = eg[(size_t)((ct + 1) * 4 + 3) * 64 + lane];
        }
        f32x16 acc;
        #pragma unroll
        for (int r = 0; r < 16; ++r) acc[r] = 0.25f;
        acc = __builtin_amdgcn_mfma_f32_32x32x16_bf16(ah0, zb[0], acc, 0, 0, 0);
        acc = __builtin_amdgcn_mfma_f32_32x32x16_bf16(ah1, zb[1], acc, 0, 0, 0);
        acc = __builtin_amdgcn_mfma_f32_32x32x16_bf16(ah2, zb[2], acc, 0, 0, 0);
        acc = __builtin_amdgcn_mfma_f32_32x32x16_bf16(ah3, zb[3], acc, 0, 0, 0);

        const int jb = ct * 32 + 4 * kh;
        #pragma unroll
        for (int r = 0; r < 16; ++r) {
            uint_t key = (__float_as_uint(acc[r]) & 0xFFFFFC00u)
                         | (uint_t)(jb + (r & 3) + 8 * (r >> 2));
            uint_t mx = max(k0, key);
            k2 = min(k2, max(k1, mx));
            k1 = min(k1, mx);
            k0 = min(k0, key);
        }
        if (ct < 31) { ah0 = nx0; ah1 = nx1; ah2 = nx2; ah3 = nx3; }
    }

    uint_t* cp = cand + (size_t)(t0 + n) * 6 + 3 * kh;
    cp[0] = k0; cp[1] = k1; cp[2] = k2;
}

// ---- EPILOGUE: threshold from 6 keys + exact rescore + gather/hist/loss/zq.
// Block = 64 tokens, 4 waves, 1024 blocks. (R13 epilogue, scan removed.)
__global__ __launch_bounds__(256, 4) void vq_epilogue(
    const float* __restrict__ z,
    const uint_t* __restrict__ cand,
    const float* __restrict__ enorm,
    const float* __restrict__ emb,
    float* __restrict__ zq,
    float* __restrict__ out_idx,
    int* __restrict__ hist,
    double* __restrict__ lossPart) {
    __shared__ float z_s[64][72];                 // [token][channel]
    __shared__ float s_zn[64];
    __shared__ unsigned long long s_res[64];      // lex-min (d_bits<<10 | j)
    __shared__ double wsum[4];

    const int tid = threadIdx.x;
    const int w = tid >> 6, lane = tid & 63;
    const int t0 = blockIdx.x * 64;
    const int b = t0 >> 12, hw0 = t0 & 4095;
    const float* zbase = z + (size_t)b * B_STRIDE + hw0;

    // stage z once, transpose into token-major LDS
    {
        const int c = tid >> 2, u0 = (tid & 3) * 16;
        const float* src = zbase + (size_t)c * CH_STRIDE + u0;
        float4 f0 = *(const float4*)(src);
        float4 f1 = *(const float4*)(src + 4);
        float4 f2 = *(const float4*)(src + 8);
        float4 f3 = *(const float4*)(src + 12);
        z_s[u0 +  0][c] = f0.x; z_s[u0 +  1][c] = f0.y;
        z_s[u0 +  2][c] = f0.z; z_s[u0 +  3][c] = f0.w;
        z_s[u0 +  4][c] = f1.x; z_s[u0 +  5][c] = f1.y;
        z_s[u0 +  6][c] = f1.z; z_s[u0 +  7][c] = f1.w;
        z_s[u0 +  8][c] = f2.x; z_s[u0 +  9][c] = f2.y;
        z_s[u0 + 10][c] = f2.z; z_s[u0 + 11][c] = f2.w;
        z_s[u0 + 12][c] = f3.x; z_s[u0 + 13][c] = f3.y;
        z_s[u0 + 14][c] = f3.z; z_s[u0 + 15][c] = f3.w;
    }
    if (tid < 64) s_res[tid] = 0xFFFFFFFFFFFFFFFFull;

    const int t_loc = tid >> 2, m = tid & 3;

    // load this thread's share of the 6 keys (s = m and m+4 when <6)
    uint_t ka = cand[(size_t)(t0 + t_loc) * 6 + m];
    uint_t kb = (m < 2) ? cand[(size_t)(t0 + t_loc) * 6 + m + 4] : 0xFFFFFFFFu;
    uint_t kmin = min(ka, kb);
    kmin = min(kmin, (uint_t)__shfl_xor((int)kmin, 1, 64));
    kmin = min(kmin, (uint_t)__shfl_xor((int)kmin, 2, 64));
    const float thr = __uint_as_float(kmin & 0xFFFFFC00u) + 4.0e-4f;

    __syncthreads();                               // z_s ready

    {   // znorm: np pairwise, exact op order; thread m owns slices m and m+4
        float a0 = z_s[t_loc][m];
        float ra = __fmul_rn(a0, a0);
        float b0 = z_s[t_loc][m + 4];
        float rb = __fmul_rn(b0, b0);
        #pragma unroll
        for (int i = 1; i < 8; ++i) {
            float av = z_s[t_loc][m + 8 * i];
            ra = __fadd_rn(ra, __fmul_rn(av, av));
            float bv = z_s[t_loc][m + 4 + 8 * i];
            rb = __fadd_rn(rb, __fmul_rn(bv, bv));
        }
        float xa = __fadd_rn(ra, __shfl_xor(ra, 1, 64));
        float A = __fadd_rn(xa, __shfl_xor(xa, 2, 64));
        float xb = __fadd_rn(rb, __shfl_xor(rb, 1, 64));
        float B = __fadd_rn(xb, __shfl_xor(xb, 2, 64));
        if (m == 0) s_zn[t_loc] = __fadd_rn(A, B);
    }
    __syncthreads();

    // exact rescore of passing candidates (expected ~1.05 per token)
    #pragma unroll
    for (int s = 0; s < 2; ++s) {
        const uint_t ck = s ? kb : ka;
        if (__uint_as_float(ck & 0xFFFFFC00u) <= thr) {
            const int j = (int)(ck & 1023u);
            const float* e = emb + (size_t)j * 64;
            float a0 = 0.f;
            #pragma unroll
            for (int k4 = 0; k4 < 16; ++k4) {
                float4 z4 = *(const float4*)&z_s[t_loc][k4 * 4];
                float4 e4 = *(const float4*)(e + k4 * 4);
                a0 = __fmaf_rn(z4.x, e4.x, a0);
                a0 = __fmaf_rn(z4.y, e4.y, a0);
                a0 = __fmaf_rn(z4.z, e4.z, a0);
                a0 = __fmaf_rn(z4.w, e4.w, a0);
            }
            float d = __fsub_rn(__fadd_rn(s_zn[t_loc], enorm[j]), 2.0f * a0);
            unsigned long long key =
                ((unsigned long long)__float_as_uint(d) << 10)
                | (unsigned long long)j;
            atomicMin(&s_res[t_loc], key);
        }
    }
    __syncthreads();

    // gather + loss: 4 threads/token, 16 contiguous channels each
    const int bj = (int)(s_res[t_loc] & 1023u);
    if (m == 0) {
        out_idx[t0 + t_loc] = (float)bj;
        atomicAdd(&hist[bj], 1);
    }
    double ls = 0.0;
    {
        const float* e = emb + (size_t)bj * 64 + m * 16;
        float4 e0 = *(const float4*)(e);
        float4 e1 = *(const float4*)(e + 4);
        float4 e2 = *(const float4*)(e + 8);
        float4 e3 = *(const float4*)(e + 12);
        float4 zv0 = *(const float4*)&z_s[t_loc][m * 16];
        float4 zv1 = *(const float4*)&z_s[t_loc][m * 16 + 4];
        float4 zv2 = *(const float4*)&z_s[t_loc][m * 16 + 8];
        float4 zv3 = *(const float4*)&z_s[t_loc][m * 16 + 12];
        float df;
        df = e0.x - zv0.x; ls += (double)(df * df);
        df = e0.y - zv0.y; ls += (double)(df * df);
        df = e0.z - zv0.z; ls += (double)(df * df);
        df = e0.w - zv0.w; ls += (double)(df * df);
        df = e1.x - zv1.x; ls += (double)(df * df);
        df = e1.y - zv1.y; ls += (double)(df * df);
        df = e1.z - zv1.z; ls += (double)(df * df);
        df = e1.w - zv1.w; ls += (double)(df * df);
        df = e2.x - zv2.x; ls += (double)(df * df);
        df = e2.y - zv2.y; ls += (double)(df * df);
        df = e2.z - zv2.z; ls += (double)(df * df);
        df = e2.w - zv2.w; ls += (double)(df * df);
        df = e3.x - zv3.x; ls += (double)(df * df);
        df = e3.y - zv3.y; ls += (double)(df * df);
        df = e3.z - zv3.z; ls += (double)(df * df);
        df = e3.w - zv3.w; ls += (double)(df * df);
        *(float4*)&z_s[t_loc][m * 16] = e0;        // tile becomes z_q
        *(float4*)&z_s[t_loc][m * 16 + 4] = e1;
        *(float4*)&z_s[t_loc][m * 16 + 8] = e2;
        *(float4*)&z_s[t_loc][m * 16 + 12] = e3;
    }
    #pragma unroll
    for (int off = 32; off > 0; off >>= 1) ls += __shfl_down(ls, off, 64);
    if (lane == 0) wsum[w] = ls;
    __syncthreads();                               // z_s fully z_q; wsum ready
    if (tid == 0)
        lossPart[blockIdx.x] = wsum[0] + wsum[1] + wsum[2] + wsum[3];

    // coalesced z_q store (transpose back out of token-major LDS)
    {
        const int c = tid >> 2, u0 = (tid & 3) * 16;
        float4 f0, f1, f2, f3;
        f0.x = z_s[u0 +  0][c]; f0.y = z_s[u0 +  1][c];
        f0.z = z_s[u0 +  2][c]; f0.w = z_s[u0 +  3][c];
        f1.x = z_s[u0 +  4][c]; f1.y = z_s[u0 +  5][c];
        f1.z = z_s[u0 +  6][c]; f1.w = z_s[u0 +  7][c];
        f2.x = z_s[u0 +  8][c]; f2.y = z_s[u0 +  9][c];
        f2.z = z_s[u0 + 10][c]; f2.w = z_s[u0 + 11][c];
        f3.x = z_s[u0 + 12][c]; f3.y = z_s[u0 + 13][c];
        f3.z = z_s[u0 + 14][c]; f3.w = z_s[u0 + 15][c];
        float* dst = zq + (size_t)b * B_STRIDE + (size_t)c * CH_STRIDE + hw0 + u0;
        *(float4*)(dst) = f0;
        *(float4*)(dst + 4) = f1;
        *(float4*)(dst + 8) = f2;
        *(float4*)(dst + 12) = f3;
    }
}

__global__ __launch_bounds__(256) void vq_final(const int* __restrict__ hist,
                                                const double* __restrict__ lossPart,
                                                float* __restrict__ outs) {
    __shared__ double red[256];
    __shared__ double red2[256];
    double acc = 0.0;
    for (int j = threadIdx.x; j < NE; j += 256) {
        double em = (double)hist[j] * (1.0 / 65536.0);
        acc += em * log(em + 1e-10);
    }
    double lsum = 0.0;
    for (int j = threadIdx.x; j < 1024; j += 256) lsum += lossPart[j];
    red[threadIdx.x] = acc;
    red2[threadIdx.x] = lsum;
    __syncthreads();
    for (int s = 128; s > 0; s >>= 1) {
        if (threadIdx.x < s) {
            red[threadIdx.x] += red[threadIdx.x + s];
            red2[threadIdx.x] += red2[threadIdx.x + s];
        }
        __syncthreads();
    }
    if (threadIdx.x == 0) {
        outs[0] = (float)(1.25 * red2[0] * (1.0 / 4194304.0));
        outs[1] = (float)exp(-red[0]);
    }
}

extern "C" void kernel_launch(void* const* d_in, const int* in_sizes, int n_in,
                              void* d_out, int out_size, void* d_ws, size_t ws_size,
                              hipStream_t stream) {
    const float* z = (const float*)d_in[0];
    const float* emb = (const float*)d_in[1];
    float* out = (float*)d_out;

    char* ws = (char*)d_ws;
    ushort_t* efrag = (ushort_t*)ws;
    float* enorm = (float*)(ws + 131072);
    int* hist = (int*)(ws + 135168);
    double* lossPart = (double*)(ws + 143360);
    uint_t* cand = (uint_t*)(ws + 151552);

    float* zq = out;                        // [0, 4194304)
    float* scalars = out + 4194304;         // loss, perplexity
    float* out_idx = out + 4194306;         // 65536 indices as float

    vq_prep_e<<<256, 256, 0, stream>>>(emb, efrag, enorm, hist);
    vq_scan<<<2048, 64, 0, stream>>>(z, efrag, cand);
    vq_epilogue<<<1024, 256, 0, stream>>>(z, cand, enorm, emb, zq, out_idx,
                                          hist, lossPart);
    vq_final<<<1, 256, 0, stream>>>(hist, lossPart, scalars);
}

// Round 15
// 56.963 us; speedup vs baseline: 1.1085x; 1.1085x over previous
//
#include <hip/hip_runtime.h>

#define TOKS 65536
#define ED 64
#define NE 1024
#define CH_STRIDE 4096      // 64*64
#define B_STRIDE 262144     // 64*64*64

typedef __bf16 bf16x8 __attribute__((ext_vector_type(8)));
typedef float f32x16 __attribute__((ext_vector_type(16)));
typedef unsigned short ushort_t;
typedef unsigned int uint_t;

// ws layout:
//   efrag    @ 0      : 32ct x 4ks x 64lane x 8 bf16 (hi of -2*emb) [128 KB]
//   enorm    @ 131072 : 1024 f32 (np-pairwise ||e||^2, exact)        [4 KB]
//   hist     @ 135168 : 1024 i32                                     [4 KB]
//   lossPart @ 143360 : 512 f64                                      [4 KB]

__device__ __forceinline__ ushort_t f2bf(float x) {
    uint_t u = __float_as_uint(x);
    uint_t r = u + 0x7FFFu + ((u >> 16) & 1u);   // RNE
    return (ushort_t)(r >> 16);
}

// ---- prep E: wave per code (unchanged, validated).
__global__ __launch_bounds__(256) void vq_prep_e(const float* __restrict__ emb,
                                                 ushort_t* __restrict__ efrag,
                                                 float* __restrict__ enorm,
                                                 int* __restrict__ hist) {
    const int tid = threadIdx.x;
    const int w = tid >> 6, lane = tid & 63;
    const int j = blockIdx.x * 4 + w;

    const float e = emb[j * 64 + lane];
    const float sq = __fmul_rn(e, e);
    float acc = sq;
    acc = __fadd_rn(acc, __shfl_down(sq, 8, 64));
    acc = __fadd_rn(acc, __shfl_down(sq, 16, 64));
    acc = __fadd_rn(acc, __shfl_down(sq, 24, 64));
    acc = __fadd_rn(acc, __shfl_down(sq, 32, 64));
    acc = __fadd_rn(acc, __shfl_down(sq, 40, 64));
    acc = __fadd_rn(acc, __shfl_down(sq, 48, 64));
    acc = __fadd_rn(acc, __shfl_down(sq, 56, 64));
    float x = __fadd_rn(acc, __shfl_down(acc, 1, 64));
    float y = __fadd_rn(x, __shfl_down(x, 2, 64));
    float zn = __fadd_rn(y, __shfl_down(y, 4, 64));
    if (lane == 0) enorm[j] = zn;

    const ushort_t h = f2bf(-2.0f * e);
    const int ct = j >> 5, m = j & 31;
    const int ks = lane >> 4, kh = (lane >> 3) & 1, i = lane & 7;
    efrag[(size_t)((ct * 4 + ks) * 512) + (m + 32 * kh) * 8 + i] = h;

    if (blockIdx.x < 4) hist[blockIdx.x * 256 + tid] = 0;
}

// ---- fused pipeline: register-resident efrag, per-tile scan+epilogue.
// 512 blocks x 512 thr (8 waves); wave owns 4 cts (128 codes, 64 VGPR);
// block processes 4 tiles of 32 tokens. Zero global loads in the scan loop.
__global__ __launch_bounds__(512, 2) void vq_main(
    const float* __restrict__ z,
    const ushort_t* __restrict__ efrag,
    const float* __restrict__ enorm,
    const float* __restrict__ emb,
    float* __restrict__ zq,
    float* __restrict__ out_idx,
    int* __restrict__ hist,
    double* __restrict__ lossPart) {
    __shared__ float z_s[2][32][68];              // [buf][token][channel]
    __shared__ uint_t skey[8][32][2][2];          // [wave][token][kh][slot]
    __shared__ unsigned long long s_res[32];      // lex-min (d_bits<<10 | j)
    __shared__ double wsum[8];

    const int tid = threadIdx.x;
    const int w = tid >> 6, lane = tid & 63;
    const int n = lane & 31, kh = lane >> 5;
    const int t0 = blockIdx.x * 128;
    const int b = t0 >> 12, hw0 = t0 & 4095;
    const float* zg = z + (size_t)b * B_STRIDE + hw0;

    // one-time: wave's 4 cts of efrag into registers (16 x b128 from L2)
    const bf16x8* eg = (const bf16x8*)efrag;
    bf16x8 ef[4][4];
    #pragma unroll
    for (int ct = 0; ct < 4; ++ct)
        #pragma unroll
        for (int ks = 0; ks < 4; ++ks)
            ef[ct][ks] = eg[(size_t)(((w * 4 + ct) * 4 + ks) * 64) + lane];

    // staging mapping: thread owns (channel sc, token-quad stk)
    const int sc = tid >> 3, stk = (tid & 7) * 4;
    const float* sbase = zg + (size_t)sc * CH_STRIDE + stk;

    float4 sreg = *(const float4*)(sbase);        // tile 0
    z_s[0][stk + 0][sc] = sreg.x; z_s[0][stk + 1][sc] = sreg.y;
    z_s[0][stk + 2][sc] = sreg.z; z_s[0][stk + 3][sc] = sreg.w;
    sreg = *(const float4*)(sbase + 32);          // tile 1 -> regs
    if (tid < 32) s_res[tid] = 0xFFFFFFFFFFFFFFFFull;
    __syncthreads();

    double ls = 0.0;
    uint_t jmask = 0xFFFFFC00u;
    const int idbase = w * 128 + 4 * kh;

    #pragma unroll 1
    for (int t = 0; t < 4; ++t) {
        const float* zs = &z_s[t & 1][0][0];
        // (a) write staged regs (tile t+1) into the other buffer
        if (t < 3) {
            float* zd = &z_s[(t + 1) & 1][0][0];
            zd[(stk + 0) * 68 + sc] = sreg.x;
            zd[(stk + 1) * 68 + sc] = sreg.y;
            zd[(stk + 2) * 68 + sc] = sreg.z;
            zd[(stk + 3) * 68 + sc] = sreg.w;
        }
        // (b) issue global load for tile t+2
        if (t < 2) sreg = *(const float4*)(sbase + (t + 2) * 32);

        // zb build from LDS (token-major row n / 32+... row n only: 32 tokens)
        bf16x8 zb[4];
        #pragma unroll
        for (int ks = 0; ks < 4; ++ks) {
            #pragma unroll
            for (int i = 0; i < 8; ++i) {
                union { ushort_t u; __bf16 bh; } cv;
                cv.u = f2bf(zs[n * 68 + ks * 16 + kh * 8 + i]);
                zb[ks][i] = cv.bh;
            }
        }

        // scan: 4 cts, register fragments, top-2 per (lane,kh) 64-code set
        uint_t k0 = 0xFFFFFFFFu, k1 = 0xFFFFFFFFu;
        #pragma unroll
        for (int ct = 0; ct < 4; ++ct) {
            f32x16 acc;
            #pragma unroll
            for (int r = 0; r < 16; ++r) acc[r] = 0.25f;
            acc = __builtin_amdgcn_mfma_f32_32x32x16_bf16(ef[ct][0], zb[0], acc, 0, 0, 0);
            acc = __builtin_amdgcn_mfma_f32_32x32x16_bf16(ef[ct][1], zb[1], acc, 0, 0, 0);
            acc = __builtin_amdgcn_mfma_f32_32x32x16_bf16(ef[ct][2], zb[2], acc, 0, 0, 0);
            acc = __builtin_amdgcn_mfma_f32_32x32x16_bf16(ef[ct][3], zb[3], acc, 0, 0, 0);
            #pragma unroll
            for (int r = 0; r < 16; ++r) {
                uint_t key = (__float_as_uint(acc[r]) & jmask)
                             | (uint_t)(idbase + ct * 32 + (r & 3) + 8 * (r >> 2));
                uint_t mx = max(k0, key);
                k1 = min(k1, mx);
                k0 = min(k0, key);
            }
        }
        skey[w][n][kh][0] = k0;
        skey[w][n][kh][1] = k1;
        __syncthreads();                           // (d) skey + stage ready

        // ---- epilogue: 16 threads per token
        const int tok = tid >> 4, p = tid & 15;
        const int tg = t0 + t * 32 + tok;          // global token
        uint_t ck0 = skey[p >> 1][tok][p & 1][0];
        uint_t ck1 = skey[p >> 1][tok][p & 1][1];
        uint_t kmin = min(ck0, ck1);
        kmin = min(kmin, (uint_t)__shfl_xor((int)kmin, 1, 64));
        kmin = min(kmin, (uint_t)__shfl_xor((int)kmin, 2, 64));
        kmin = min(kmin, (uint_t)__shfl_xor((int)kmin, 4, 64));
        kmin = min(kmin, (uint_t)__shfl_xor((int)kmin, 8, 64));
        const float thr = __uint_as_float(kmin & jmask) + 4.0e-4f;

        // znorm: np pairwise exact; slice m = p&7, shfl_xor(1,2,4) combine
        float zn;
        {
            const int m = p & 7;
            float a = zs[tok * 68 + m];
            float racc = __fmul_rn(a, a);
            #pragma unroll
            for (int i = 1; i < 8; ++i) {
                float av = zs[tok * 68 + m + 8 * i];
                racc = __fadd_rn(racc, __fmul_rn(av, av));
            }
            float x1 = __fadd_rn(racc, __shfl_xor(racc, 1, 64));
            float y1 = __fadd_rn(x1, __shfl_xor(x1, 2, 64));
            zn = __fadd_rn(y1, __shfl_xor(y1, 4, 64));
        }

        // exact rescore of this thread's passing keys (rare)
        #pragma unroll
        for (int s = 0; s < 2; ++s) {
            const uint_t ck = s ? ck1 : ck0;
            if (__uint_as_float(ck & jmask) <= thr) {
                const int j = (int)(ck & 1023u);
                const float* e = emb + (size_t)j * 64;
                float a0 = 0.f;
                #pragma unroll
                for (int k4 = 0; k4 < 16; ++k4) {
                    float4 z4 = *(const float4*)&zs[tok * 68 + k4 * 4];
                    float4 e4 = *(const float4*)(e + k4 * 4);
                    a0 = __fmaf_rn(z4.x, e4.x, a0);
                    a0 = __fmaf_rn(z4.y, e4.y, a0);
                    a0 = __fmaf_rn(z4.z, e4.z, a0);
                    a0 = __fmaf_rn(z4.w, e4.w, a0);
                }
                float d = __fsub_rn(__fadd_rn(zn, enorm[j]), 2.0f * a0);
                unsigned long long key =
                    ((unsigned long long)__float_as_uint(d) << 10)
                    | (unsigned long long)j;
                atomicMin(&s_res[tok], key);
            }
        }
        __syncthreads();                           // (f) s_res final

        // gather + loss: thread owns 4 contiguous channels p*4..p*4+3
        const int bj = (int)(s_res[tok] & 1023u);
        if (p == 0) {
            out_idx[tg] = (float)bj;
            atomicAdd(&hist[bj], 1);
        }
        {
            float4 e4 = *(const float4*)(emb + (size_t)bj * 64 + p * 4);
            float* zrow = (float*)&z_s[t & 1][tok][p * 4];
            float df;
            df = e4.x - zrow[0]; ls += (double)(df * df);
            df = e4.y - zrow[1]; ls += (double)(df * df);
            df = e4.z - zrow[2]; ls += (double)(df * df);
            df = e4.w - zrow[3]; ls += (double)(df * df);
            zrow[0] = e4.x; zrow[1] = e4.y; zrow[2] = e4.z; zrow[3] = e4.w;
        }
        __syncthreads();                           // (h) z_s is now z_q

        // coalesced z_q store (from token-major LDS)
        {
            float4 f;
            f.x = z_s[t & 1][stk + 0][sc];
            f.y = z_s[t & 1][stk + 1][sc];
            f.z = z_s[t & 1][stk + 2][sc];
            f.w = z_s[t & 1][stk + 3][sc];
            *(float4*)(zq + (size_t)b * B_STRIDE + (size_t)sc * CH_STRIDE
                       + hw0 + t * 32 + stk) = f;
        }
        if (tid < 32) s_res[tid] = 0xFFFFFFFFFFFFFFFFull;
        __syncthreads();                           // (i) buffer/s_res safe
    }

    // loss reduction: wave -> block -> lossPart[block]
    #pragma unroll
    for (int off = 32; off > 0; off >>= 1) ls += __shfl_down(ls, off, 64);
    if (lane == 0) wsum[w] = ls;
    __syncthreads();
    if (tid == 0) {
        double tot = 0.0;
        #pragma unroll
        for (int i = 0; i < 8; ++i) tot += wsum[i];
        lossPart[blockIdx.x] = tot;
    }
}

__global__ __launch_bounds__(256) void vq_final(const int* __restrict__ hist,
                                                const double* __restrict__ lossPart,
                                                float* __restrict__ outs) {
    __shared__ double red[256];
    __shared__ double red2[256];
    double acc = 0.0;
    for (int j = threadIdx.x; j < NE; j += 256) {
        double em = (double)hist[j] * (1.0 / 65536.0);
        acc += em * log(em + 1e-10);
    }
    double lsum = 0.0;
    for (int j = threadIdx.x; j < 512; j += 256) lsum += lossPart[j];
    red[threadIdx.x] = acc;
    red2[threadIdx.x] = lsum;
    __syncthreads();
    for (int s = 128; s > 0; s >>= 1) {
        if (threadIdx.x < s) {
            red[threadIdx.x] += red[threadIdx.x + s];
            red2[threadIdx.x] += red2[threadIdx.x + s];
        }
        __syncthreads();
    }
    if (threadIdx.x == 0) {
        outs[0] = (float)(1.25 * red2[0] * (1.0 / 4194304.0));
        outs[1] = (float)exp(-red[0]);
    }
}

extern "C" void kernel_launch(void* const* d_in, const int* in_sizes, int n_in,
                              void* d_out, int out_size, void* d_ws, size_t ws_size,
                              hipStream_t stream) {
    const float* z = (const float*)d_in[0];
    const float* emb = (const float*)d_in[1];
    float* out = (float*)d_out;

    char* ws = (char*)d_ws;
    ushort_t* efrag = (ushort_t*)ws;
    float* enorm = (float*)(ws + 131072);
    int* hist = (int*)(ws + 135168);
    double* lossPart = (double*)(ws + 143360);

    float* zq = out;                        // [0, 4194304)
    float* scalars = out + 4194304;         // loss, perplexity
    float* out_idx = out + 4194306;         // 65536 indices as float

    vq_prep_e<<<256, 256, 0, stream>>>(emb, efrag, enorm, hist);
    vq_main<<<512, 512, 0, stream>>>(z, efrag, enorm, emb, zq, out_idx,
                                     hist, lossPart);
    vq_final<<<1, 256, 0, stream>>>(hist, lossPart, scalars);
}

// Round 16
// 45.264 us; speedup vs baseline: 1.3949x; 1.2584x over previous
//
#include <hip/hip_runtime.h>

#define TOKS 65536
#define ED 64
#define NE 1024
#define CH_STRIDE 4096      // 64*64
#define B_STRIDE 262144     // 64*64*64

typedef __bf16 bf16x8 __attribute__((ext_vector_type(8)));
typedef float f32x16 __attribute__((ext_vector_type(16)));
typedef unsigned short ushort_t;
typedef unsigned int uint_t;

// ws layout:
//   efrag    @ 0      : 32ct x 4ks x 64lane x 8 bf16 (hi of -2*emb) [128 KB]
//   enorm    @ 131072 : 1024 f32 (np-pairwise ||e||^2, exact)        [4 KB]
//   hist     @ 135168 : 1024 i32                                     [4 KB]
//   lossPart @ 143360 : 2048 f64                                     [16 KB]

__device__ __forceinline__ ushort_t f2bf(float x) {
    uint_t u = __float_as_uint(x);
    uint_t r = u + 0x7FFFu + ((u >> 16) & 1u);   // RNE
    return (ushort_t)(r >> 16);
}

// ---- prep E: wave per code (unchanged, validated).
__global__ __launch_bounds__(256) void vq_prep_e(const float* __restrict__ emb,
                                                 ushort_t* __restrict__ efrag,
                                                 float* __restrict__ enorm,
                                                 int* __restrict__ hist) {
    const int tid = threadIdx.x;
    const int w = tid >> 6, lane = tid & 63;
    const int j = blockIdx.x * 4 + w;

    const float e = emb[j * 64 + lane];
    const float sq = __fmul_rn(e, e);
    float acc = sq;
    acc = __fadd_rn(acc, __shfl_down(sq, 8, 64));
    acc = __fadd_rn(acc, __shfl_down(sq, 16, 64));
    acc = __fadd_rn(acc, __shfl_down(sq, 24, 64));
    acc = __fadd_rn(acc, __shfl_down(sq, 32, 64));
    acc = __fadd_rn(acc, __shfl_down(sq, 40, 64));
    acc = __fadd_rn(acc, __shfl_down(sq, 48, 64));
    acc = __fadd_rn(acc, __shfl_down(sq, 56, 64));
    float x = __fadd_rn(acc, __shfl_down(acc, 1, 64));
    float y = __fadd_rn(x, __shfl_down(x, 2, 64));
    float zn = __fadd_rn(y, __shfl_down(y, 4, 64));
    if (lane == 0) enorm[j] = zn;

    const ushort_t h = f2bf(-2.0f * e);
    const int ct = j >> 5, m = j & 31;
    const int ks = lane >> 4, kh = (lane >> 3) & 1, i = lane & 7;
    efrag[(size_t)((ct * 4 + ks) * 512) + (m + 32 * kh) * 8 + i] = h;

    if (blockIdx.x < 4) hist[blockIdx.x * 256 + tid] = 0;
}

// ---- fused: 32-token blocks, 2048 blocks, ~10 KB LDS, natural VGPR<=64
// -> 8 blocks/CU resident (the clean high-occupancy experiment).
__global__ __launch_bounds__(256, 4) void vq_main(
    const float* __restrict__ z,
    const ushort_t* __restrict__ efrag,
    const float* __restrict__ enorm,
    const float* __restrict__ emb,
    float* __restrict__ zq,
    float* __restrict__ out_idx,
    int* __restrict__ hist,
    double* __restrict__ lossPart) {
    __shared__ float z_s[32][68];                 // [token][channel], 8.7 KB
    __shared__ uint_t skey[4][32][2];             // [wave][token][slot], 1 KB
    __shared__ unsigned long long s_res[32];      // lex-min (d_bits<<10 | j)
    __shared__ double wsum[4];

    const int tid = threadIdx.x;
    const int w = tid >> 6, lane = tid & 63;
    const int t0 = blockIdx.x * 32;
    const int b = t0 >> 12, hw0 = t0 & 4095;
    const float* zbase = z + (size_t)b * B_STRIDE + hw0;

    // stage z once: thread (c, u0) loads 8 floats, transposes to token-major
    {
        const int c = tid >> 2, u0 = (tid & 3) * 8;
        const float* src = zbase + (size_t)c * CH_STRIDE + u0;
        float4 f0 = *(const float4*)(src);
        float4 f1 = *(const float4*)(src + 4);
        z_s[u0 + 0][c] = f0.x; z_s[u0 + 1][c] = f0.y;
        z_s[u0 + 2][c] = f0.z; z_s[u0 + 3][c] = f0.w;
        z_s[u0 + 4][c] = f1.x; z_s[u0 + 5][c] = f1.y;
        z_s[u0 + 6][c] = f1.z; z_s[u0 + 7][c] = f1.w;
    }
    if (tid < 32) s_res[tid] = 0xFFFFFFFFFFFFFFFFull;
    __syncthreads();

    const int n = lane & 31, kh = lane >> 5;

    // B-frag from LDS (b128 contiguous rows)
    bf16x8 zb[4];
    #pragma unroll
    for (int ks = 0; ks < 4; ++ks) {
        float4 a0 = *(const float4*)&z_s[n][ks * 16 + kh * 8];
        float4 a1 = *(const float4*)&z_s[n][ks * 16 + kh * 8 + 4];
        const float av[8] = {a0.x, a0.y, a0.z, a0.w, a1.x, a1.y, a1.z, a1.w};
        #pragma unroll
        for (int i = 0; i < 8; ++i) {
            union { ushort_t u; __bf16 bh; } cv;
            cv.u = f2bf(av[i]);
            zb[ks][i] = cv.bh;
        }
    }

    uint_t k0 = 0xFFFFFFFFu, k1 = 0xFFFFFFFFu;
    const bf16x8* eg = (const bf16x8*)efrag;
    const int rot = blockIdx.x & 7;                // de-lockstep co-residents

    int gct = w * 8 + rot;
    bf16x8 ah0 = eg[(size_t)(gct * 4 + 0) * 64 + lane];
    bf16x8 ah1 = eg[(size_t)(gct * 4 + 1) * 64 + lane];
    bf16x8 ah2 = eg[(size_t)(gct * 4 + 2) * 64 + lane];
    bf16x8 ah3 = eg[(size_t)(gct * 4 + 3) * 64 + lane];

    for (int ct = 0; ct < 8; ++ct) {
        const int gnext = w * 8 + ((ct + 1 + rot) & 7);
        bf16x8 nx0, nx1, nx2, nx3;
        if (ct < 7) {                              // 1-deep prefetch
            nx0 = eg[(size_t)(gnext * 4 + 0) * 64 + lane];
            nx1 = eg[(size_t)(gnext * 4 + 1) * 64 + lane];
            nx2 = eg[(size_t)(gnext * 4 + 2) * 64 + lane];
            nx3 = eg[(size_t)(gnext * 4 + 3) * 64 + lane];
        }
        const int jb = gct * 32 + 4 * kh;

        f32x16 acc;
        #pragma unroll
        for (int r = 0; r < 16; ++r) acc[r] = 0.25f;
        acc = __builtin_amdgcn_mfma_f32_32x32x16_bf16(ah0, zb[0], acc, 0, 0, 0);
        acc = __builtin_amdgcn_mfma_f32_32x32x16_bf16(ah1, zb[1], acc, 0, 0, 0);
        acc = __builtin_amdgcn_mfma_f32_32x32x16_bf16(ah2, zb[2], acc, 0, 0, 0);
        acc = __builtin_amdgcn_mfma_f32_32x32x16_bf16(ah3, zb[3], acc, 0, 0, 0);

        #pragma unroll
        for (int r = 0; r < 16; ++r) {
            uint_t key = (__float_as_uint(acc[r]) & 0xFFFFFC00u)
                         | (uint_t)(jb + (r & 3) + 8 * (r >> 2));
            uint_t mx = max(k0, key);
            k1 = min(k1, mx);
            k0 = min(k0, key);
        }
        ah0 = nx0; ah1 = nx1; ah2 = nx2; ah3 = nx3;
        gct = gnext;
    }

    // merge kh halves: top-2 of this wave's 256-code set per token column
    {
        uint_t p0 = (uint_t)__shfl_xor((int)k0, 32, 64);
        uint_t p1 = (uint_t)__shfl_xor((int)k1, 32, 64);
        uint_t o0 = min(k0, p0);
        uint_t o1 = min(max(k0, p0), min(k1, p1));
        if (kh == 0) { skey[w][n][0] = o0; skey[w][n][1] = o1; }
    }
    __syncthreads();

    // ---- epilogue: 8 threads per token, 1 key each
    const int tok = tid >> 3, p = tid & 7;
    const uint_t ck = skey[p >> 1][tok][p & 1];
    uint_t kmin = ck;
    kmin = min(kmin, (uint_t)__shfl_xor((int)kmin, 1, 64));
    kmin = min(kmin, (uint_t)__shfl_xor((int)kmin, 2, 64));
    kmin = min(kmin, (uint_t)__shfl_xor((int)kmin, 4, 64));
    const float thr = __uint_as_float(kmin & 0xFFFFFC00u) + 4.0e-4f;

    // znorm: np pairwise exact (slice p of 8, xor 1/2/4 butterfly = np tree)
    float zn;
    {
        float a = z_s[tok][p];
        float racc = __fmul_rn(a, a);
        #pragma unroll
        for (int i = 1; i < 8; ++i) {
            float av = z_s[tok][p + 8 * i];
            racc = __fadd_rn(racc, __fmul_rn(av, av));
        }
        float x1 = __fadd_rn(racc, __shfl_xor(racc, 1, 64));
        float y1 = __fadd_rn(x1, __shfl_xor(x1, 2, 64));
        zn = __fadd_rn(y1, __shfl_xor(y1, 4, 64));
    }

    // exact rescore of this thread's key if in window (expected ~1.1/token)
    if (__uint_as_float(ck & 0xFFFFFC00u) <= thr) {
        const int j = (int)(ck & 1023u);
        const float* e = emb + (size_t)j * 64;
        float a0 = 0.f;
        #pragma unroll
        for (int k4 = 0; k4 < 16; ++k4) {
            float4 z4 = *(const float4*)&z_s[tok][k4 * 4];
            float4 e4 = *(const float4*)(e + k4 * 4);
            a0 = __fmaf_rn(z4.x, e4.x, a0);
            a0 = __fmaf_rn(z4.y, e4.y, a0);
            a0 = __fmaf_rn(z4.z, e4.z, a0);
            a0 = __fmaf_rn(z4.w, e4.w, a0);
        }
        float d = __fsub_rn(__fadd_rn(zn, enorm[j]), 2.0f * a0);
        unsigned long long key =
            ((unsigned long long)__float_as_uint(d) << 10)
            | (unsigned long long)j;
        atomicMin(&s_res[tok], key);
    }
    __syncthreads();

    // gather + loss: 8 threads/token, 8 contiguous channels each
    const int bj = (int)(s_res[tok] & 1023u);
    if (p == 0) {
        out_idx[t0 + tok] = (float)bj;
        atomicAdd(&hist[bj], 1);
    }
    double ls = 0.0;
    {
        const float* e = emb + (size_t)bj * 64 + p * 8;
        float4 e0 = *(const float4*)(e);
        float4 e1 = *(const float4*)(e + 4);
        float4 zv0 = *(const float4*)&z_s[tok][p * 8];
        float4 zv1 = *(const float4*)&z_s[tok][p * 8 + 4];
        float df;
        df = e0.x - zv0.x; ls += (double)(df * df);
        df = e0.y - zv0.y; ls += (double)(df * df);
        df = e0.z - zv0.z; ls += (double)(df * df);
        df = e0.w - zv0.w; ls += (double)(df * df);
        df = e1.x - zv1.x; ls += (double)(df * df);
        df = e1.y - zv1.y; ls += (double)(df * df);
        df = e1.z - zv1.z; ls += (double)(df * df);
        df = e1.w - zv1.w; ls += (double)(df * df);
        *(float4*)&z_s[tok][p * 8] = e0;           // tile becomes z_q
        *(float4*)&z_s[tok][p * 8 + 4] = e1;
    }
    #pragma unroll
    for (int off = 32; off > 0; off >>= 1) ls += __shfl_down(ls, off, 64);
    if (lane == 0) wsum[w] = ls;
    __syncthreads();                               // z_s fully z_q; wsum ready
    if (tid == 0)
        lossPart[blockIdx.x] = wsum[0] + wsum[1] + wsum[2] + wsum[3];

    // coalesced z_q store (transpose back out of token-major LDS)
    {
        const int c = tid >> 2, u0 = (tid & 3) * 8;
        float4 f0, f1;
        f0.x = z_s[u0 + 0][c]; f0.y = z_s[u0 + 1][c];
        f0.z = z_s[u0 + 2][c]; f0.w = z_s[u0 + 3][c];
        f1.x = z_s[u0 + 4][c]; f1.y = z_s[u0 + 5][c];
        f1.z = z_s[u0 + 6][c]; f1.w = z_s[u0 + 7][c];
        float* dst = zq + (size_t)b * B_STRIDE + (size_t)c * CH_STRIDE + hw0 + u0;
        *(float4*)(dst) = f0;
        *(float4*)(dst + 4) = f1;
    }
}

__global__ __launch_bounds__(256) void vq_final(const int* __restrict__ hist,
                                                const double* __restrict__ lossPart,
                                                float* __restrict__ outs) {
    __shared__ double red[256];
    __shared__ double red2[256];
    double acc = 0.0;
    for (int j = threadIdx.x; j < NE; j += 256) {
        double em = (double)hist[j] * (1.0 / 65536.0);
        acc += em * log(em + 1e-10);
    }
    double lsum = 0.0;
    for (int j = threadIdx.x; j < 2048; j += 256) lsum += lossPart[j];
    red[threadIdx.x] = acc;
    red2[threadIdx.x] = lsum;
    __syncthreads();
    for (int s = 128; s > 0; s >>= 1) {
        if (threadIdx.x < s) {
            red[threadIdx.x] += red[threadIdx.x + s];
            red2[threadIdx.x] += red2[threadIdx.x + s];
        }
        __syncthreads();
    }
    if (threadIdx.x == 0) {
        outs[0] = (float)(1.25 * red2[0] * (1.0 / 4194304.0));
        outs[1] = (float)exp(-red[0]);
    }
}

extern "C" void kernel_launch(void* const* d_in, const int* in_sizes, int n_in,
                              void* d_out, int out_size, void* d_ws, size_t ws_size,
                              hipStream_t stream) {
    const float* z = (const float*)d_in[0];
    const float* emb = (const float*)d_in[1];
    float* out = (float*)d_out;

    char* ws = (char*)d_ws;
    ushort_t* efrag = (ushort_t*)ws;
    float* enorm = (float*)(ws + 131072);
    int* hist = (int*)(ws + 135168);
    double* lossPart = (double*)(ws + 143360);

    float* zq = out;                        // [0, 4194304)
    float* scalars = out + 4194304;         // loss, perplexity
    float* out_idx = out + 4194306;         // 65536 indices as float

    vq_prep_e<<<256, 256, 0, stream>>>(emb, efrag, enorm, hist);
    vq_main<<<2048, 256, 0, stream>>>(z, efrag, enorm, emb, zq, out_idx,
                                      hist, lossPart);
    vq_final<<<1, 256, 0, stream>>>(hist, lossPart, scalars);
}